// Round 5
// baseline (233.383 us; speedup 1.0000x reference)
//
#include <hip/hip_runtime.h>
#include <hip/hip_fp16.h>
#include <stdint.h>

// GAT: N=4096, F=512, H=8, D=64.
// score(h,i,j) = leaky(es_i + en_j); exp(leaky-M) = max(c1*u, c2*v) with
//   u=exp(en), v=exp(0.2*en), c1=exp(es-M), c2=exp(0.2*es-M); mask = AND with
//   bit-packed A; fixed per-row M => no softmax state, j-partials additive.
//
// attn: block = 64 rows x 1 head = 16 waves (2 row-halves x 8 j-eighths),
// grid 512 (h = bx&7 -> head h pinned to XCD h), 2 blocks/CU = 8 waves/SIMD.
// No LDS/barriers in the main loop; 3-barrier jq-tree reduction at the end.

#define NODES 4096
#define FEAT  512
#define HEADS 8
#define DH    64
#define NT    (NODES / 64)

using half2v = __attribute__((ext_vector_type(2))) _Float16;
using half8  = __attribute__((ext_vector_type(8))) _Float16;
using f32x4  = __attribute__((ext_vector_type(4))) float;

#if defined(__has_builtin)
#if __has_builtin(__builtin_amdgcn_fdot2)
#define HAS_FDOT2 1
#endif
#endif

__device__ __forceinline__ uint32_t fenc(float f) {
    uint32_t u = __float_as_uint(f);
    return (u >> 31) ? ~u : (u | 0x80000000u);
}
__device__ __forceinline__ float fdec(uint32_t e) {
    uint32_t u = (e >> 31) ? (e & 0x7FFFFFFFu) : ~e;
    return __uint_as_float(u);
}

// ---------------- pack: A -> transposed bitmask, one wave per u64 word ----------------
// AbitsT[wc][row] = bits of A[row][wc*64 .. +64)
__global__ __launch_bounds__(1024) void pack_kernel(const float* __restrict__ A,
                                                    uint64_t* __restrict__ AbitsT) {
    const int w    = threadIdx.x >> 6;
    const int lane = threadIdx.x & 63;
    const int widx = blockIdx.x * 16 + w;
    const int wc   = widx & 63;
    const int row  = widx >> 6;
    uint64_t m = __ballot(A[(size_t)row * NODES + wc * 64 + lane] != 0.0f);
    if (lane == 0) AbitsT[(size_t)wc * NODES + row] = m;
}

// ---------------- cast: X -> f16 (vectorized) ----------------
__global__ __launch_bounds__(256) void cast_kernel(const float* __restrict__ X,
                                                   _Float16* __restrict__ Xh) {
    int i = (blockIdx.x * 256 + threadIdx.x) * 4;
    f32x4 x = *(const f32x4*)(X + i);
    half2v a = half2v{(_Float16)x[0], (_Float16)x[1]};
    half2v b = half2v{(_Float16)x[2], (_Float16)x[3]};
    *(half2v*)(Xh + i)     = a;
    *(half2v*)(Xh + i + 2) = b;
}

// ---------------- wtrans: W[h][f][d] -> WT[h][d][f] f16 via LDS tile ----------------
__global__ __launch_bounds__(256) void wtrans_kernel(const float* __restrict__ W,
                                                     _Float16* __restrict__ WT) {
    __shared__ float t[64][65];
    const int h  = blockIdx.x >> 3;
    const int ft = blockIdx.x & 7;
    const int r  = threadIdx.x >> 6;   // 0..3
    const int c  = threadIdx.x & 63;
#pragma unroll
    for (int r0 = 0; r0 < 64; r0 += 4)
        t[r0 + r][c] = W[((size_t)h * FEAT + ft * 64 + r0 + r) * DH + c];
    __syncthreads();
#pragma unroll
    for (int r0 = 0; r0 < 64; r0 += 4)
        WT[((size_t)h * DH + r0 + r) * FEAT + ft * 64 + c] = (_Float16)t[c][r0 + r];
}

// ---------------- feats: Vt tiled [h][jt][d][jj] f16 + e_self/u/v + enmax ----------------
__global__ __launch_bounds__(256) void feats_kernel(
    const _Float16* __restrict__ Xh, const _Float16* __restrict__ WT,
    const float* __restrict__ a_self, const float* __restrict__ a_neigh,
    _Float16* __restrict__ Vt, float* __restrict__ e_self,
    _Float16* __restrict__ u_tab, _Float16* __restrict__ v_tab,
    uint32_t* __restrict__ enmax_u) {
    const int h    = blockIdx.y;
    const int tid  = threadIdx.x;
    const int w    = tid >> 6;
    const int lane = tid & 63;
    const int l15  = lane & 15;
    const int g    = lane >> 4;
    const int bx   = blockIdx.x;
    const int n0   = bx * 64 + w * 16;

    f32x4 acc[4] = {};
    const _Float16* xb = Xh + (n0 + l15) * FEAT + g * 8;
    const _Float16* wb = WT + (h * DH + l15) * FEAT + g * 8;

#pragma unroll
    for (int kk = 0; kk < FEAT / 32; ++kk) {
        half8 b = *(const half8*)(xb + kk * 32);
#pragma unroll
        for (int mi = 0; mi < 4; ++mi) {
            half8 a = *(const half8*)(wb + mi * 16 * FEAT + kk * 32);
            acc[mi] = __builtin_amdgcn_mfma_f32_16x16x32_f16(a, b, acc[mi], 0, 0, 0);
        }
    }

    float ps = 0.f, pn = 0.f;
#pragma unroll
    for (int mi = 0; mi < 4; ++mi) {
#pragma unroll
        for (int r = 0; r < 4; ++r) {
            int d = mi * 16 + g * 4 + r;
            float v = acc[mi][r];
            Vt[((size_t)h * NT + bx) * 4096 + d * 64 + w * 16 + l15] = (_Float16)v;
            ps += v * a_self[h * DH + d];
            pn += v * a_neigh[h * DH + d];
        }
    }
    ps += __shfl_xor(ps, 16); ps += __shfl_xor(ps, 32);
    pn += __shfl_xor(pn, 16); pn += __shfl_xor(pn, 32);
    if (g == 0) {
        int n = n0 + l15;
        e_self[h * NODES + n] = ps;
        u_tab[h * NODES + n]  = (_Float16)__expf(pn);
        v_tab[h * NODES + n]  = (_Float16)__expf(0.2f * pn);
    }
    float mx = pn;
    mx = fmaxf(mx, __shfl_xor(mx, 1));
    mx = fmaxf(mx, __shfl_xor(mx, 2));
    mx = fmaxf(mx, __shfl_xor(mx, 4));
    mx = fmaxf(mx, __shfl_xor(mx, 8));
    if (lane == 0) atomicMax(enmax_u + h, fenc(mx));
}

// ---------------- attn ----------------
// grid 512, 1024 threads = 16 waves. wave w: rh = w&1 (32 rows), jq = w>>1
// (j in [jq*512, +512), 8 steps of 64). h = bx&7, i0 = (bx>>3)*64.
__global__ __launch_bounds__(1024, 8) void attn_kernel(
    const uint64_t* __restrict__ AbitsT, const _Float16* __restrict__ Vt,
    const float* __restrict__ e_self, const _Float16* __restrict__ u_tab,
    const _Float16* __restrict__ v_tab, const uint32_t* __restrict__ enmax_u,
    const float* __restrict__ bias, float* __restrict__ out) {
    __shared__ float red[2][4][32][68];
    __shared__ float psr[2][4][32];

    const int tid  = threadIdx.x;
    const int w    = tid >> 6;
    const int lane = tid & 63;
    const int l15  = lane & 15;
    const int g    = lane >> 4;
    const int g8   = g * 8;
    const int rh   = w & 1;
    const int jq   = w >> 1;
    const int h    = blockIdx.x & 7;
    const int i0   = (blockIdx.x >> 3) * 64;

    half2v c1h[2], c2h[2];
    const float em = fdec(enmax_u[h]);
#pragma unroll
    for (int mi = 0; mi < 2; ++mi) {
        float es = e_self[h * NODES + i0 + rh * 32 + mi * 16 + l15];
        float t  = es + em;
        float M  = fmaxf(t, 0.2f * t);
        _Float16 c1 = (_Float16)__expf(es - M);
        _Float16 c2 = (_Float16)__expf(0.2f * es - M);
        c1h[mi] = half2v{c1, c1};
        c2h[mi] = half2v{c2, c2};
    }

    const _Float16* ub = u_tab + h * NODES;
    const _Float16* vb = v_tab + h * NODES;
    const uint64_t* abase = AbitsT + i0 + rh * 32 + l15;
    const _Float16* vtbase = Vt + (size_t)h * NT * 4096 + (size_t)l15 * 64 + g8;

    f32x4 acc[2][4] = {};
    float psf[2] = {0.f, 0.f};
    const half2v one2 = half2v{(_Float16)1.0f, (_Float16)1.0f};

    for (int s = 0; s < 8; ++s) {
        const int jt = jq * 8 + s;
        const int j0 = jt * 64;
        const uint64_t wb0 = abase[(size_t)jt * NODES];
        const uint64_t wb1 = abase[(size_t)jt * NODES + 16];
        const _Float16* vp = vtbase + (size_t)jt * 4096;
#pragma unroll
        for (int kk = 0; kk < 2; ++kk) {
            const half8 uf = *(const half8*)(ub + j0 + kk * 32 + g8);
            const half8 vf = *(const half8*)(vb + j0 + kk * 32 + g8);
            const uint32_t b0 = ((uint32_t)(wb0 >> (kk * 32)) >> g8) & 0xFFu;
            const uint32_t b1 = ((uint32_t)(wb1 >> (kk * 32)) >> g8) & 0xFFu;
            half8 paf0, paf1;
#pragma unroll
            for (int q = 0; q < 4; ++q) {
                half2v u2 = half2v{uf[2 * q], uf[2 * q + 1]};
                half2v v2 = half2v{vf[2 * q], vf[2 * q + 1]};
                // sign-extended bit masks -> bfi idiom
                uint32_t w0lo = (uint32_t)(-(int32_t)((b0 >> (2 * q)) & 1u));
                uint32_t w0hi = (uint32_t)(-(int32_t)((b0 >> (2 * q + 1)) & 1u));
                uint32_t w1lo = (uint32_t)(-(int32_t)((b1 >> (2 * q)) & 1u));
                uint32_t w1hi = (uint32_t)(-(int32_t)((b1 >> (2 * q + 1)) & 1u));
                uint32_t m0 = (w0hi & 0xFFFF0000u) | (w0lo & 0xFFFFu);
                uint32_t m1 = (w1hi & 0xFFFF0000u) | (w1lo & 0xFFFFu);
                half2v p0 = __builtin_elementwise_max(u2 * c1h[0], v2 * c2h[0]);
                half2v p1 = __builtin_elementwise_max(u2 * c1h[1], v2 * c2h[1]);
                p0 = __builtin_bit_cast(half2v, __builtin_bit_cast(uint32_t, p0) & m0);
                p1 = __builtin_bit_cast(half2v, __builtin_bit_cast(uint32_t, p1) & m1);
#ifdef HAS_FDOT2
                psf[0] = __builtin_amdgcn_fdot2(p0, one2, psf[0], false);
                psf[1] = __builtin_amdgcn_fdot2(p1, one2, psf[1], false);
#else
                psf[0] += (float)p0[0] + (float)p0[1];
                psf[1] += (float)p1[0] + (float)p1[1];
#endif
                paf0[2 * q] = p0[0]; paf0[2 * q + 1] = p0[1];
                paf1[2 * q] = p1[0]; paf1[2 * q + 1] = p1[1];
            }
#pragma unroll
            for (int ni = 0; ni < 4; ++ni) {
                const half8 vfr = *(const half8*)(vp + ni * 1024 + kk * 32);
                acc[0][ni] = __builtin_amdgcn_mfma_f32_16x16x32_f16(paf0, vfr, acc[0][ni], 0, 0, 0);
                acc[1][ni] = __builtin_amdgcn_mfma_f32_16x16x32_f16(paf1, vfr, acc[1][ni], 0, 0, 0);
            }
        }
    }

    // row sums uniform across g
#pragma unroll
    for (int mi = 0; mi < 2; ++mi) {
        psf[mi] += __shfl_xor(psf[mi], 16);
        psf[mi] += __shfl_xor(psf[mi], 32);
    }

    // ---- jq-tree reduction (3 barriers): 8 -> 4 -> 2 -> 1 ----
    // r0: odd jq -> slot jq>>1
    if (jq & 1) {
#pragma unroll
        for (int mi = 0; mi < 2; ++mi) {
#pragma unroll
            for (int ni = 0; ni < 4; ++ni)
#pragma unroll
                for (int r = 0; r < 4; ++r)
                    red[rh][jq >> 1][mi * 16 + g * 4 + r][ni * 16 + l15] = acc[mi][ni][r];
            if (g == 0) psr[rh][jq >> 1][mi * 16 + l15] = psf[mi];
        }
    }
    __syncthreads();
    if (!(jq & 1)) {
#pragma unroll
        for (int mi = 0; mi < 2; ++mi) {
#pragma unroll
            for (int ni = 0; ni < 4; ++ni)
#pragma unroll
                for (int r = 0; r < 4; ++r)
                    acc[mi][ni][r] += red[rh][jq >> 1][mi * 16 + g * 4 + r][ni * 16 + l15];
            psf[mi] += psr[rh][jq >> 1][mi * 16 + l15];
        }
        if (jq == 4 || jq == 6) {   // write own slot (2,3) - safe, own read done
#pragma unroll
            for (int mi = 0; mi < 2; ++mi) {
#pragma unroll
                for (int ni = 0; ni < 4; ++ni)
#pragma unroll
                    for (int r = 0; r < 4; ++r)
                        red[rh][jq >> 1][mi * 16 + g * 4 + r][ni * 16 + l15] = acc[mi][ni][r];
                if (g == 0) psr[rh][jq >> 1][mi * 16 + l15] = psf[mi];
            }
        }
    }
    __syncthreads();
    if (jq == 0 || jq == 2) {
#pragma unroll
        for (int mi = 0; mi < 2; ++mi) {
#pragma unroll
            for (int ni = 0; ni < 4; ++ni)
#pragma unroll
                for (int r = 0; r < 4; ++r)
                    acc[mi][ni][r] += red[rh][(jq >> 1) + 2][mi * 16 + g * 4 + r][ni * 16 + l15];
            psf[mi] += psr[rh][(jq >> 1) + 2][mi * 16 + l15];
        }
        if (jq == 2) {   // own slot 3
#pragma unroll
            for (int mi = 0; mi < 2; ++mi) {
#pragma unroll
                for (int ni = 0; ni < 4; ++ni)
#pragma unroll
                    for (int r = 0; r < 4; ++r)
                        red[rh][3][mi * 16 + g * 4 + r][ni * 16 + l15] = acc[mi][ni][r];
                if (g == 0) psr[rh][3][mi * 16 + l15] = psf[mi];
            }
        }
    }
    __syncthreads();
    if (jq == 0) {
#pragma unroll
        for (int mi = 0; mi < 2; ++mi) {
#pragma unroll
            for (int ni = 0; ni < 4; ++ni)
#pragma unroll
                for (int r = 0; r < 4; ++r)
                    acc[mi][ni][r] += red[rh][3][mi * 16 + g * 4 + r][ni * 16 + l15];
            psf[mi] += psr[rh][3][mi * 16 + l15];
        }
        // epilogue: rows = i0 + rh*32 + mi*16 + g*4 + r, col = h*64 + ni*16 + l15
#pragma unroll
        for (int mi = 0; mi < 2; ++mi) {
            float invr[4];
#pragma unroll
            for (int r = 0; r < 4; ++r)
                invr[r] = 1.0f / __shfl(psf[mi], g * 4 + r);
#pragma unroll
            for (int ni = 0; ni < 4; ++ni) {
                float bb = bias[h * DH + ni * 16 + l15];
#pragma unroll
                for (int r = 0; r < 4; ++r) {
                    float v = acc[mi][ni][r] * invr[r] + bb;
                    out[(size_t)(i0 + rh * 32 + mi * 16 + g * 4 + r) * (HEADS * DH) + h * DH + ni * 16 + l15] =
                        fmaxf(v, 0.f);
                }
            }
        }
    }
}

extern "C" void kernel_launch(void* const* d_in, const int* in_sizes, int n_in,
                              void* d_out, int out_size, void* d_ws, size_t ws_size,
                              hipStream_t stream) {
    const float* X       = (const float*)d_in[0];
    const float* A       = (const float*)d_in[1];
    const float* W       = (const float*)d_in[2];
    const float* b       = (const float*)d_in[3];
    const float* a_self  = (const float*)d_in[4];
    const float* a_neigh = (const float*)d_in[5];
    float* out = (float*)d_out;

    char* ws = (char*)d_ws;
    size_t off = 0;
    uint64_t* AbitsT = (uint64_t*)(ws + off); off += (size_t)64 * NODES * 8;          // 2 MB
    _Float16* Xh     = (_Float16*)(ws + off); off += (size_t)NODES * FEAT * 2;        // 4 MB
    _Float16* WT     = (_Float16*)(ws + off); off += (size_t)HEADS * DH * FEAT * 2;   // 512 KB
    _Float16* Vt     = (_Float16*)(ws + off); off += (size_t)HEADS * DH * NODES * 2;  // 4 MB
    float* e_self    = (float*)(ws + off);    off += (size_t)HEADS * NODES * 4;       // 128 KB
    _Float16* u_tab  = (_Float16*)(ws + off); off += (size_t)HEADS * NODES * 2;       // 64 KB
    _Float16* v_tab  = (_Float16*)(ws + off); off += (size_t)HEADS * NODES * 2;       // 64 KB
    uint32_t* enmax_u = (uint32_t*)(ws + off); off += 64;

    hipMemsetAsync(enmax_u, 0, 64, stream);

    pack_kernel<<<NODES * 64 / 16, 1024, 0, stream>>>(A, AbitsT);
    cast_kernel<<<NODES * FEAT / 4 / 256, 256, 0, stream>>>(X, Xh);
    wtrans_kernel<<<HEADS * 8, 256, 0, stream>>>(W, WT);
    feats_kernel<<<dim3(NODES / 64, HEADS), 256, 0, stream>>>(
        Xh, WT, a_self, a_neigh, Vt, e_self, u_tab, v_tab, enmax_u);
    attn_kernel<<<(NODES / 64) * HEADS, 1024, 0, stream>>>(
        AbitsT, Vt, e_self, u_tab, v_tab, enmax_u, b, out);
}

// Round 6
// 194.659 us; speedup vs baseline: 1.1989x; 1.1989x over previous
//
#include <hip/hip_runtime.h>
#include <hip/hip_fp16.h>
#include <stdint.h>

// GAT: N=4096, F=512, H=8, D=64.
// score(h,i,j) = leaky(es_i + en_j); exp(leaky-M) = max(c1*u, c2*v) with
//   u=exp(en), v=exp(0.2*en), c1=exp(es-M), c2=exp(0.2*es-M); mask = AND with
//   bit-packed A; fixed per-row M => no softmax state, j-partials additive.
//
// attn: block = 64 rows x 1 head = 16 waves (4 row-quarters x 4 j-quarters),
// grid 512 (h = bx&7 -> head pinned per XCD), 2 blocks/CU = 32 waves/CU,
// <=64 VGPR per wave by construction (16-row acc = 16 VGPRs). One barrier.

#define NODES 4096
#define FEAT  512
#define HEADS 8
#define DH    64
#define NT    (NODES / 64)

using half2v = __attribute__((ext_vector_type(2))) _Float16;
using half8  = __attribute__((ext_vector_type(8))) _Float16;
using f32x4  = __attribute__((ext_vector_type(4))) float;

#if defined(__has_builtin)
#if __has_builtin(__builtin_amdgcn_fdot2)
#define HAS_FDOT2 1
#endif
#endif

__device__ __forceinline__ uint32_t fenc(float f) {
    uint32_t u = __float_as_uint(f);
    return (u >> 31) ? ~u : (u | 0x80000000u);
}
__device__ __forceinline__ float fdec(uint32_t e) {
    uint32_t u = (e >> 31) ? (e & 0x7FFFFFFFu) : ~e;
    return __uint_as_float(u);
}

// ---------------- prep (merged): A->bits | X->f16 | W->WT ----------------
#define PACK_BLOCKS 16384
#define CAST_BLOCKS (NODES * FEAT / 4 / 256)   // 2048
#define WT_BLOCKS   (HEADS * 8)                // 64

__global__ __launch_bounds__(256) void prep_kernel(
    const float* __restrict__ A, const float* __restrict__ X, const float* __restrict__ W,
    uint64_t* __restrict__ AbitsT, _Float16* __restrict__ Xh, _Float16* __restrict__ WT) {
    __shared__ float t[64][65];
    const int bx = blockIdx.x;
    if (bx < PACK_BLOCKS) {
        // AbitsT[wc][row] = bits of A[row][wc*64 .. +64); one wave per word
        const int w    = threadIdx.x >> 6;
        const int lane = threadIdx.x & 63;
#pragma unroll
        for (int tt = 0; tt < 4; ++tt) {
            const int widx = bx * 16 + w * 4 + tt;
            const int row  = widx >> 6;
            const int wc   = widx & 63;
            uint64_t m = __ballot(A[(size_t)row * NODES + wc * 64 + lane] != 0.0f);
            if (lane == 0) AbitsT[(size_t)wc * NODES + row] = m;
        }
        return;
    }
    if (bx < PACK_BLOCKS + CAST_BLOCKS) {
        int i = ((bx - PACK_BLOCKS) * 256 + threadIdx.x) * 4;
        f32x4 x = *(const f32x4*)(X + i);
        *(half2v*)(Xh + i)     = half2v{(_Float16)x[0], (_Float16)x[1]};
        *(half2v*)(Xh + i + 2) = half2v{(_Float16)x[2], (_Float16)x[3]};
        return;
    }
    // W[h][f][d] -> WT[h][d][f] via LDS tile
    const int b2 = bx - PACK_BLOCKS - CAST_BLOCKS;
    const int h  = b2 >> 3;
    const int ft = b2 & 7;
    const int r  = threadIdx.x >> 6;
    const int c  = threadIdx.x & 63;
#pragma unroll
    for (int r0 = 0; r0 < 64; r0 += 4)
        t[r0 + r][c] = W[((size_t)h * FEAT + ft * 64 + r0 + r) * DH + c];
    __syncthreads();
#pragma unroll
    for (int r0 = 0; r0 < 64; r0 += 4)
        WT[((size_t)h * DH + r0 + r) * FEAT + ft * 64 + c] = (_Float16)t[c][r0 + r];
}

// ---------------- feats: 4-way K-split per block, grid (256 n-tiles x 8 heads) ----------------
// block 256 thr = 4 waves; wave w computes K-range [w*128, +128) for a 16-col
// n-tile x 64 d; LDS-combine; wave 0 epilogue (Vt tiled + e/u/v + enmax).
__global__ __launch_bounds__(256) void feats_kernel(
    const _Float16* __restrict__ Xh, const _Float16* __restrict__ WT,
    const float* __restrict__ a_self, const float* __restrict__ a_neigh,
    _Float16* __restrict__ Vt, float* __restrict__ e_self,
    _Float16* __restrict__ u_tab, _Float16* __restrict__ v_tab,
    uint32_t* __restrict__ enmax_u) {
    __shared__ float cmb[3][64][17];
    const int h    = blockIdx.y;
    const int bx   = blockIdx.x;          // n-tile: cols bx*16..+16
    const int tid  = threadIdx.x;
    const int w    = tid >> 6;
    const int lane = tid & 63;
    const int l15  = lane & 15;
    const int g    = lane >> 4;
    const int n0   = bx * 16;

    f32x4 acc[4] = {};
    const _Float16* xb = Xh + (n0 + l15) * FEAT + g * 8;
    const _Float16* wb = WT + (h * DH + l15) * FEAT + g * 8;

#pragma unroll
    for (int kk = 0; kk < 4; ++kk) {
        const int k = (w * 4 + kk) * 32;
        half8 b = *(const half8*)(xb + k);
#pragma unroll
        for (int mi = 0; mi < 4; ++mi) {
            half8 a = *(const half8*)(wb + mi * 16 * FEAT + k);
            acc[mi] = __builtin_amdgcn_mfma_f32_16x16x32_f16(a, b, acc[mi], 0, 0, 0);
        }
    }

    if (w > 0) {
#pragma unroll
        for (int mi = 0; mi < 4; ++mi)
#pragma unroll
            for (int r = 0; r < 4; ++r)
                cmb[w - 1][mi * 16 + g * 4 + r][l15] = acc[mi][r];
    }
    __syncthreads();
    if (w == 0) {
        float ps = 0.f, pn = 0.f;
#pragma unroll
        for (int mi = 0; mi < 4; ++mi) {
#pragma unroll
            for (int r = 0; r < 4; ++r) {
                int d = mi * 16 + g * 4 + r;
                float v = acc[mi][r] + cmb[0][d][l15] + cmb[1][d][l15] + cmb[2][d][l15];
                Vt[((size_t)h * NT + (bx >> 2)) * 4096 + d * 64 + (bx & 3) * 16 + l15] = (_Float16)v;
                ps += v * a_self[h * DH + d];
                pn += v * a_neigh[h * DH + d];
            }
        }
        ps += __shfl_xor(ps, 16); ps += __shfl_xor(ps, 32);
        pn += __shfl_xor(pn, 16); pn += __shfl_xor(pn, 32);
        if (g == 0) {
            int n = n0 + l15;
            e_self[h * NODES + n] = ps;
            u_tab[h * NODES + n]  = (_Float16)__expf(pn);
            v_tab[h * NODES + n]  = (_Float16)__expf(0.2f * pn);
        }
        float mx = pn;
        mx = fmaxf(mx, __shfl_xor(mx, 1));
        mx = fmaxf(mx, __shfl_xor(mx, 2));
        mx = fmaxf(mx, __shfl_xor(mx, 4));
        mx = fmaxf(mx, __shfl_xor(mx, 8));
        if (lane == 0) atomicMax(enmax_u + h, fenc(mx));
    }
}

// ---------------- attn ----------------
// grid 512 (64 i-tiles x 8 heads), 1024 thr = 16 waves: rh = w&3 (16 rows),
// jq = w>>2 (1024 cols, 16 steps of 64). One barrier; jq0 combines + epilogue.
__global__ __launch_bounds__(1024, 8) void attn_kernel(
    const uint64_t* __restrict__ AbitsT, const _Float16* __restrict__ Vt,
    const float* __restrict__ e_self, const _Float16* __restrict__ u_tab,
    const _Float16* __restrict__ v_tab, const uint32_t* __restrict__ enmax_u,
    const float* __restrict__ bias, float* __restrict__ out) {
    __shared__ float red[4][3][16][68];
    __shared__ float psr[4][3][16];

    const int tid  = threadIdx.x;
    const int w    = tid >> 6;
    const int lane = tid & 63;
    const int l15  = lane & 15;
    const int g    = lane >> 4;
    const int g8   = g * 8;
    const int rh   = w & 3;
    const int jq   = w >> 2;
    const int h    = blockIdx.x & 7;
    const int i0   = (blockIdx.x >> 3) * 64;

    const float em = fdec(enmax_u[h]);
    const float es = e_self[h * NODES + i0 + rh * 16 + l15];
    const float t0 = es + em;
    const float M  = fmaxf(t0, 0.2f * t0);
    const _Float16 c1 = (_Float16)__expf(es - M);
    const _Float16 c2 = (_Float16)__expf(0.2f * es - M);
    const half2v c1h = half2v{c1, c1};
    const half2v c2h = half2v{c2, c2};

    const _Float16* ub = u_tab + h * NODES;
    const _Float16* vb = v_tab + h * NODES;
    const uint64_t* abase = AbitsT + i0 + rh * 16 + l15;
    const _Float16* vtbase = Vt + (size_t)h * NT * 4096 + (size_t)l15 * 64 + g8;

    f32x4 acc[4] = {};
    float psf = 0.f;
    const half2v one2 = half2v{(_Float16)1.0f, (_Float16)1.0f};

#pragma unroll 2
    for (int s = 0; s < 16; ++s) {
        const int jt = jq * 16 + s;
        const int j0 = jt * 64;
        const uint64_t wbits = abase[(size_t)jt * NODES];
        const _Float16* vp = vtbase + (size_t)jt * 4096;
#pragma unroll
        for (int kk = 0; kk < 2; ++kk) {
            const half8 uf = *(const half8*)(ub + j0 + kk * 32 + g8);
            const half8 vf = *(const half8*)(vb + j0 + kk * 32 + g8);
            const uint32_t b0 = ((uint32_t)(wbits >> (kk * 32)) >> g8) & 0xFFu;
            half8 paf;
#pragma unroll
            for (int q = 0; q < 4; ++q) {
                half2v u2 = half2v{uf[2 * q], uf[2 * q + 1]};
                half2v v2 = half2v{vf[2 * q], vf[2 * q + 1]};
                half2v p2 = __builtin_elementwise_max(u2 * c1h, v2 * c2h);
                uint32_t mlo = (uint32_t)(-(int32_t)((b0 >> (2 * q)) & 1u));
                uint32_t mhi = (uint32_t)(-(int32_t)((b0 >> (2 * q + 1)) & 1u));
                uint32_t m = (mhi & 0xFFFF0000u) | (mlo & 0xFFFFu);
                p2 = __builtin_bit_cast(half2v, __builtin_bit_cast(uint32_t, p2) & m);
#ifdef HAS_FDOT2
                psf = __builtin_amdgcn_fdot2(p2, one2, psf, false);
#else
                psf += (float)p2[0] + (float)p2[1];
#endif
                paf[2 * q] = p2[0]; paf[2 * q + 1] = p2[1];
            }
#pragma unroll
            for (int ni = 0; ni < 4; ++ni) {
                const half8 vfr = *(const half8*)(vp + ni * 1024 + kk * 32);
                acc[ni] = __builtin_amdgcn_mfma_f32_16x16x32_f16(paf, vfr, acc[ni], 0, 0, 0);
            }
        }
    }

    psf += __shfl_xor(psf, 16);
    psf += __shfl_xor(psf, 32);

    if (jq > 0) {
#pragma unroll
        for (int ni = 0; ni < 4; ++ni)
#pragma unroll
            for (int r = 0; r < 4; ++r)
                red[rh][jq - 1][g * 4 + r][ni * 16 + l15] = acc[ni][r];
        if (g == 0) psr[rh][jq - 1][l15] = psf;
    }
    __syncthreads();
    if (jq == 0) {
#pragma unroll
        for (int ni = 0; ni < 4; ++ni)
#pragma unroll
            for (int r = 0; r < 4; ++r)
                acc[ni][r] += red[rh][0][g * 4 + r][ni * 16 + l15] +
                              red[rh][1][g * 4 + r][ni * 16 + l15] +
                              red[rh][2][g * 4 + r][ni * 16 + l15];
        psf += psr[rh][0][l15] + psr[rh][1][l15] + psr[rh][2][l15];

        float invr[4];
#pragma unroll
        for (int r = 0; r < 4; ++r)
            invr[r] = 1.0f / __shfl(psf, g * 4 + r);
#pragma unroll
        for (int ni = 0; ni < 4; ++ni) {
            float bb = bias[h * DH + ni * 16 + l15];
#pragma unroll
            for (int r = 0; r < 4; ++r) {
                float v = acc[ni][r] * invr[r] + bb;
                out[(size_t)(i0 + rh * 16 + g * 4 + r) * (HEADS * DH) + h * DH + ni * 16 + l15] =
                    fmaxf(v, 0.f);
            }
        }
    }
}

extern "C" void kernel_launch(void* const* d_in, const int* in_sizes, int n_in,
                              void* d_out, int out_size, void* d_ws, size_t ws_size,
                              hipStream_t stream) {
    const float* X       = (const float*)d_in[0];
    const float* A       = (const float*)d_in[1];
    const float* W       = (const float*)d_in[2];
    const float* b       = (const float*)d_in[3];
    const float* a_self  = (const float*)d_in[4];
    const float* a_neigh = (const float*)d_in[5];
    float* out = (float*)d_out;

    char* ws = (char*)d_ws;
    size_t off = 0;
    uint64_t* AbitsT = (uint64_t*)(ws + off); off += (size_t)64 * NODES * 8;          // 2 MB
    _Float16* Xh     = (_Float16*)(ws + off); off += (size_t)NODES * FEAT * 2;        // 4 MB
    _Float16* WT     = (_Float16*)(ws + off); off += (size_t)HEADS * DH * FEAT * 2;   // 512 KB
    _Float16* Vt     = (_Float16*)(ws + off); off += (size_t)HEADS * DH * NODES * 2;  // 4 MB
    float* e_self    = (float*)(ws + off);    off += (size_t)HEADS * NODES * 4;       // 128 KB
    _Float16* u_tab  = (_Float16*)(ws + off); off += (size_t)HEADS * NODES * 2;       // 64 KB
    _Float16* v_tab  = (_Float16*)(ws + off); off += (size_t)HEADS * NODES * 2;       // 64 KB
    uint32_t* enmax_u = (uint32_t*)(ws + off); off += 64;

    hipMemsetAsync(enmax_u, 0, 64, stream);

    prep_kernel<<<PACK_BLOCKS + CAST_BLOCKS + WT_BLOCKS, 256, 0, stream>>>(
        A, X, W, AbitsT, Xh, WT);
    feats_kernel<<<dim3(NODES / 16, HEADS), 256, 0, stream>>>(
        Xh, WT, a_self, a_neigh, Vt, e_self, u_tab, v_tab, enmax_u);
    attn_kernel<<<(NODES / 64) * HEADS, 1024, 0, stream>>>(
        AbitsT, Vt, e_self, u_tab, v_tab, enmax_u, b, out);
}

// Round 7
// 120.380 us; speedup vs baseline: 1.9387x; 1.6170x over previous
//
#include <hip/hip_runtime.h>
#include <hip/hip_fp16.h>
#include <stdint.h>

// GAT: N=4096, F=512, H=8, D=64.
// score(h,i,j) = leaky(es_i + en_j); exp(leaky-M) = max(c1*u, c2*v) with
//   u=exp(en), v=exp(0.2*en), c1=exp(es-M), c2=exp(0.2*es-M); mask = AND with
//   bit-packed A; fixed per-row M => no softmax state, j-partials additive.
//
// attn: block = 64 rows x 1 head = 16 waves (4 row-quarters x 4 j-quarters).
// V tiles staged in LDS via global_load_lds (double-buffered, 1 barrier/step),
// shared by the 4 rh-waves of each jq -> no per-wave V duplication, and the
// V path is LDS-latency (~12cy) instead of L2 (~300cy). grid 512, 2 blocks/CU.

#define NODES 4096
#define FEAT  512
#define HEADS 8
#define DH    64
#define NT    (NODES / 64)

using half2v = __attribute__((ext_vector_type(2))) _Float16;
using half8  = __attribute__((ext_vector_type(8))) _Float16;
using f32x4  = __attribute__((ext_vector_type(4))) float;

#if defined(__has_builtin)
#if __has_builtin(__builtin_amdgcn_fdot2)
#define HAS_FDOT2 1
#endif
#endif

__device__ __forceinline__ void gll16(const void* g, void* l) {
    __builtin_amdgcn_global_load_lds(
        (const __attribute__((address_space(1))) uint32_t*)g,
        (__attribute__((address_space(3))) uint32_t*)l, 16, 0, 0);
}

__device__ __forceinline__ uint32_t fenc(float f) {
    uint32_t u = __float_as_uint(f);
    return (u >> 31) ? ~u : (u | 0x80000000u);
}
__device__ __forceinline__ float fdec(uint32_t e) {
    uint32_t u = (e >> 31) ? (e & 0x7FFFFFFFu) : ~e;
    return __uint_as_float(u);
}

// ---------------- prep (merged): A->bits | X->f16 | W->WT ----------------
#define PACK_BLOCKS 16384
#define CAST_BLOCKS (NODES * FEAT / 4 / 256)   // 2048
#define WT_BLOCKS   (HEADS * 8)                // 64

__global__ __launch_bounds__(256) void prep_kernel(
    const float* __restrict__ A, const float* __restrict__ X, const float* __restrict__ W,
    uint64_t* __restrict__ AbitsT, _Float16* __restrict__ Xh, _Float16* __restrict__ WT) {
    __shared__ float t[64][65];
    const int bx = blockIdx.x;
    if (bx < PACK_BLOCKS) {
        // AbitsT[wc][row] = bits of A[row][wc*64 .. +64); one wave per word
        const int w    = threadIdx.x >> 6;
        const int lane = threadIdx.x & 63;
#pragma unroll
        for (int tt = 0; tt < 4; ++tt) {
            const int widx = bx * 16 + w * 4 + tt;
            const int row  = widx >> 6;
            const int wc   = widx & 63;
            uint64_t m = __ballot(A[(size_t)row * NODES + wc * 64 + lane] != 0.0f);
            if (lane == 0) AbitsT[(size_t)wc * NODES + row] = m;
        }
        return;
    }
    if (bx < PACK_BLOCKS + CAST_BLOCKS) {
        int i = ((bx - PACK_BLOCKS) * 256 + threadIdx.x) * 4;
        f32x4 x = *(const f32x4*)(X + i);
        *(half2v*)(Xh + i)     = half2v{(_Float16)x[0], (_Float16)x[1]};
        *(half2v*)(Xh + i + 2) = half2v{(_Float16)x[2], (_Float16)x[3]};
        return;
    }
    // W[h][f][d] -> WT[h][d][f] via LDS tile
    const int b2 = bx - PACK_BLOCKS - CAST_BLOCKS;
    const int h  = b2 >> 3;
    const int ft = b2 & 7;
    const int r  = threadIdx.x >> 6;
    const int c  = threadIdx.x & 63;
#pragma unroll
    for (int r0 = 0; r0 < 64; r0 += 4)
        t[r0 + r][c] = W[((size_t)h * FEAT + ft * 64 + r0 + r) * DH + c];
    __syncthreads();
#pragma unroll
    for (int r0 = 0; r0 < 64; r0 += 4)
        WT[((size_t)h * DH + r0 + r) * FEAT + ft * 64 + c] = (_Float16)t[c][r0 + r];
}

// ---------------- feats: 4-way K-split per block, grid (256 n-tiles x 8 heads) ----------------
__global__ __launch_bounds__(256) void feats_kernel(
    const _Float16* __restrict__ Xh, const _Float16* __restrict__ WT,
    const float* __restrict__ a_self, const float* __restrict__ a_neigh,
    _Float16* __restrict__ Vt, float* __restrict__ e_self,
    _Float16* __restrict__ u_tab, _Float16* __restrict__ v_tab,
    uint32_t* __restrict__ enmax_u) {
    __shared__ float cmb[3][64][17];
    const int h    = blockIdx.y;
    const int bx   = blockIdx.x;          // n-tile: cols bx*16..+16
    const int tid  = threadIdx.x;
    const int w    = tid >> 6;
    const int lane = tid & 63;
    const int l15  = lane & 15;
    const int g    = lane >> 4;
    const int n0   = bx * 16;

    f32x4 acc[4] = {};
    const _Float16* xb = Xh + (n0 + l15) * FEAT + g * 8;
    const _Float16* wb = WT + (h * DH + l15) * FEAT + g * 8;

#pragma unroll
    for (int kk = 0; kk < 4; ++kk) {
        const int k = (w * 4 + kk) * 32;
        half8 b = *(const half8*)(xb + k);
#pragma unroll
        for (int mi = 0; mi < 4; ++mi) {
            half8 a = *(const half8*)(wb + mi * 16 * FEAT + k);
            acc[mi] = __builtin_amdgcn_mfma_f32_16x16x32_f16(a, b, acc[mi], 0, 0, 0);
        }
    }

    if (w > 0) {
#pragma unroll
        for (int mi = 0; mi < 4; ++mi)
#pragma unroll
            for (int r = 0; r < 4; ++r)
                cmb[w - 1][mi * 16 + g * 4 + r][l15] = acc[mi][r];
    }
    __syncthreads();
    if (w == 0) {
        float ps = 0.f, pn = 0.f;
#pragma unroll
        for (int mi = 0; mi < 4; ++mi) {
#pragma unroll
            for (int r = 0; r < 4; ++r) {
                int d = mi * 16 + g * 4 + r;
                float v = acc[mi][r] + cmb[0][d][l15] + cmb[1][d][l15] + cmb[2][d][l15];
                Vt[((size_t)h * NT + (bx >> 2)) * 4096 + d * 64 + (bx & 3) * 16 + l15] = (_Float16)v;
                ps += v * a_self[h * DH + d];
                pn += v * a_neigh[h * DH + d];
            }
        }
        ps += __shfl_xor(ps, 16); ps += __shfl_xor(ps, 32);
        pn += __shfl_xor(pn, 16); pn += __shfl_xor(pn, 32);
        if (g == 0) {
            int n = n0 + l15;
            e_self[h * NODES + n] = ps;
            u_tab[h * NODES + n]  = (_Float16)__expf(pn);
            v_tab[h * NODES + n]  = (_Float16)__expf(0.2f * pn);
        }
        float mx = pn;
        mx = fmaxf(mx, __shfl_xor(mx, 1));
        mx = fmaxf(mx, __shfl_xor(mx, 2));
        mx = fmaxf(mx, __shfl_xor(mx, 4));
        mx = fmaxf(mx, __shfl_xor(mx, 8));
        if (lane == 0) atomicMax(enmax_u + h, fenc(mx));
    }
}

// ---------------- attn ----------------
// grid 512 (64 i-tiles x 8 heads), 1024 thr = 16 waves: rh = w&3 (16 rows),
// jq = w>>2 (1024 cols, 16 steps of 64). V tile [cc 0..7][d 0..63][8] f16 in
// LDS, double-buffered per jq; staged by jq's own 4 waves via global_load_lds.
__global__ __launch_bounds__(1024, 8) void attn_kernel(
    const uint64_t* __restrict__ AbitsT, const _Float16* __restrict__ Vt,
    const float* __restrict__ e_self, const _Float16* __restrict__ u_tab,
    const _Float16* __restrict__ v_tab, const uint32_t* __restrict__ enmax_u,
    const float* __restrict__ bias, float* __restrict__ out) {
    // 64 KB: Vlds[jq 0..3][buf 0..1][4096 f16]; reused as float red[] after loop
    __shared__ __align__(16) char smem[4 * 2 * 4096 * 2];
    _Float16* Vlds = (_Float16*)smem;
    float*    redf = (float*)smem;
    // red(rh,slot,row,col) = redf[((rh*3+slot)*16+row)*68+col]   (52224 B)
    // psr(rh,slot,row)     = redf[13056 + (rh*3+slot)*16+row]    (+768 B)

    const int tid  = threadIdx.x;
    const int w    = tid >> 6;
    const int lane = tid & 63;
    const int l15  = lane & 15;
    const int g    = lane >> 4;
    const int g8   = g * 8;
    const int rh   = w & 3;
    const int jq   = w >> 2;
    const int h    = blockIdx.x & 7;
    const int i0   = (blockIdx.x >> 3) * 64;

    const float em = fdec(enmax_u[h]);
    const float es = e_self[h * NODES + i0 + rh * 16 + l15];
    const float t0 = es + em;
    const float M  = fmaxf(t0, 0.2f * t0);
    const _Float16 c1 = (_Float16)__expf(es - M);
    const _Float16 c2 = (_Float16)__expf(0.2f * es - M);
    const half2v c1h = half2v{c1, c1};
    const half2v c2h = half2v{c2, c2};

    const _Float16* ub = u_tab + h * NODES;
    const _Float16* vb = v_tab + h * NODES;
    const uint64_t* abase = AbitsT + i0 + rh * 16 + l15;
    // tile s source base; per-thread src covers chunk (d=lane, cc=rh*2+p)
    const _Float16* vtile0 = Vt + (size_t)(h * NT + jq * 16) * 4096 + lane * 64 + rh * 16;
    // dest: Vlds[jq][buf] + chunk_idx*8, chunk_idx = rh*128 + p*64 + lane
    _Float16* vdst0 = Vlds + jq * 8192 + rh * 1024;

#define STAGE(s_, buf_) do {                                        \
        const _Float16* vs_ = vtile0 + (size_t)(s_) * 4096;         \
        _Float16* vd_ = vdst0 + (buf_) * 4096;                      \
        gll16(vs_, vd_);                                            \
        gll16(vs_ + 8, vd_ + 512);                                  \
    } while (0)

    f32x4 acc[4] = {};
    float psf = 0.f;
    const half2v one2 = half2v{(_Float16)1.0f, (_Float16)1.0f};

    STAGE(0, 0);
    __syncthreads();

#pragma unroll 2
    for (int s = 0; s < 16; ++s) {
        const int buf = s & 1;
        if (s + 1 < 16) STAGE(s + 1, buf ^ 1);

        const int jt = jq * 16 + s;
        const int j0 = jt * 64;
        const uint64_t wbits = abase[(size_t)jt * NODES];
        const _Float16* vl = Vlds + jq * 8192 + buf * 4096;
#pragma unroll
        for (int kk = 0; kk < 2; ++kk) {
            const half8 uf = *(const half8*)(ub + j0 + kk * 32 + g8);
            const half8 vf = *(const half8*)(vb + j0 + kk * 32 + g8);
            const uint32_t b0 = ((uint32_t)(wbits >> (kk * 32)) >> g8) & 0xFFu;
            half8 paf;
#pragma unroll
            for (int q = 0; q < 4; ++q) {
                half2v u2 = half2v{uf[2 * q], uf[2 * q + 1]};
                half2v v2 = half2v{vf[2 * q], vf[2 * q + 1]};
                half2v p2 = __builtin_elementwise_max(u2 * c1h, v2 * c2h);
                uint32_t mlo = (uint32_t)(-(int32_t)((b0 >> (2 * q)) & 1u));
                uint32_t mhi = (uint32_t)(-(int32_t)((b0 >> (2 * q + 1)) & 1u));
                uint32_t m = (mhi & 0xFFFF0000u) | (mlo & 0xFFFFu);
                p2 = __builtin_bit_cast(half2v, __builtin_bit_cast(uint32_t, p2) & m);
#ifdef HAS_FDOT2
                psf = __builtin_amdgcn_fdot2(p2, one2, psf, false);
#else
                psf += (float)p2[0] + (float)p2[1];
#endif
                paf[2 * q] = p2[0]; paf[2 * q + 1] = p2[1];
            }
#pragma unroll
            for (int ni = 0; ni < 4; ++ni) {
                const half8 vfr = *(const half8*)(vl + (kk * 4 + g) * 512 + (ni * 16 + l15) * 8);
                acc[ni] = __builtin_amdgcn_mfma_f32_16x16x32_f16(paf, vfr, acc[ni], 0, 0, 0);
            }
        }
        __syncthreads();
    }

    psf += __shfl_xor(psf, 16);
    psf += __shfl_xor(psf, 32);

    // ---- in-block jq reduction in the (now free) V-LDS space ----
    if (jq > 0) {
#pragma unroll
        for (int ni = 0; ni < 4; ++ni)
#pragma unroll
            for (int r = 0; r < 4; ++r)
                redf[((rh * 3 + (jq - 1)) * 16 + g * 4 + r) * 68 + ni * 16 + l15] = acc[ni][r];
        if (g == 0) redf[13056 + (rh * 3 + (jq - 1)) * 16 + l15] = psf;
    }
    __syncthreads();
    if (jq == 0) {
#pragma unroll
        for (int ni = 0; ni < 4; ++ni)
#pragma unroll
            for (int r = 0; r < 4; ++r)
                acc[ni][r] += redf[((rh * 3 + 0) * 16 + g * 4 + r) * 68 + ni * 16 + l15] +
                              redf[((rh * 3 + 1) * 16 + g * 4 + r) * 68 + ni * 16 + l15] +
                              redf[((rh * 3 + 2) * 16 + g * 4 + r) * 68 + ni * 16 + l15];
        psf += redf[13056 + (rh * 3 + 0) * 16 + l15] +
               redf[13056 + (rh * 3 + 1) * 16 + l15] +
               redf[13056 + (rh * 3 + 2) * 16 + l15];

        float invr[4];
#pragma unroll
        for (int r = 0; r < 4; ++r)
            invr[r] = 1.0f / __shfl(psf, g * 4 + r);
#pragma unroll
        for (int ni = 0; ni < 4; ++ni) {
            float bb = bias[h * DH + ni * 16 + l15];
#pragma unroll
            for (int r = 0; r < 4; ++r) {
                float v = acc[ni][r] * invr[r] + bb;
                out[(size_t)(i0 + rh * 16 + g * 4 + r) * (HEADS * DH) + h * DH + ni * 16 + l15] =
                    fmaxf(v, 0.f);
            }
        }
    }
#undef STAGE
}

extern "C" void kernel_launch(void* const* d_in, const int* in_sizes, int n_in,
                              void* d_out, int out_size, void* d_ws, size_t ws_size,
                              hipStream_t stream) {
    const float* X       = (const float*)d_in[0];
    const float* A       = (const float*)d_in[1];
    const float* W       = (const float*)d_in[2];
    const float* b       = (const float*)d_in[3];
    const float* a_self  = (const float*)d_in[4];
    const float* a_neigh = (const float*)d_in[5];
    float* out = (float*)d_out;

    char* ws = (char*)d_ws;
    size_t off = 0;
    uint64_t* AbitsT = (uint64_t*)(ws + off); off += (size_t)64 * NODES * 8;          // 2 MB
    _Float16* Xh     = (_Float16*)(ws + off); off += (size_t)NODES * FEAT * 2;        // 4 MB
    _Float16* WT     = (_Float16*)(ws + off); off += (size_t)HEADS * DH * FEAT * 2;   // 512 KB
    _Float16* Vt     = (_Float16*)(ws + off); off += (size_t)HEADS * DH * NODES * 2;  // 4 MB
    float* e_self    = (float*)(ws + off);    off += (size_t)HEADS * NODES * 4;       // 128 KB
    _Float16* u_tab  = (_Float16*)(ws + off); off += (size_t)HEADS * NODES * 2;       // 64 KB
    _Float16* v_tab  = (_Float16*)(ws + off); off += (size_t)HEADS * NODES * 2;       // 64 KB
    uint32_t* enmax_u = (uint32_t*)(ws + off); off += 64;

    hipMemsetAsync(enmax_u, 0, 64, stream);

    prep_kernel<<<PACK_BLOCKS + CAST_BLOCKS + WT_BLOCKS, 256, 0, stream>>>(
        A, X, W, AbitsT, Xh, WT);
    feats_kernel<<<dim3(NODES / 16, HEADS), 256, 0, stream>>>(
        Xh, WT, a_self, a_neigh, Vt, e_self, u_tab, v_tab, enmax_u);
    attn_kernel<<<(NODES / 64) * HEADS, 1024, 0, stream>>>(
        AbitsT, Vt, e_self, u_tab, v_tab, enmax_u, b, out);
}